// Round 1
// baseline (847.658 us; speedup 1.0000x reference)
//
#include <hip/hip_runtime.h>
#include <hip/hip_bf16.h>
#include <math.h>

// Problem constants
#define MM 2048   // context length
#define NN 256    // entities
#define LL 128    // query length
#define DD 300    // d2
#define D2 600    // 2*D
#define D4 1200   // 4*D
#define DROOT 17.320508075688775f

__device__ __forceinline__ float sigmoidf_(float x) { return 1.f / (1.f + expf(-x)); }

// ---------------------------------------------------------------- K1: tok2ent
// ent[n][0:D]=mean over all M (zeros included) ; ent[n][D:2D]=max (zeros included)
__global__ __launch_bounds__(320) void k_tok2ent(const float* __restrict__ ctx,
                                                 const float* __restrict__ binM,
                                                 float* __restrict__ ent) {
    int n = blockIdx.x, d = threadIdx.x;
    if (d >= DD) return;
    float sum = 0.f, mx = 0.f;  // max includes the zeros of non-members
    for (int m = 0; m < MM; ++m) {
        float b = binM[m * NN + n];       // uniform across threads
        if (b != 0.f) {
            float v = ctx[m * DD + d];
            sum += v;
            mx = fmaxf(mx, v);
        }
    }
    ent[n * D2 + d]      = sum * (1.f / MM);
    ent[n * D2 + DD + d] = mx;
}

// ---------------------------------------------------------------- K2a: query mean pool
__global__ __launch_bounds__(320) void k_qpool(const float* __restrict__ query,
                                               float* __restrict__ qpool) {
    int d = threadIdx.x;
    if (d >= DD) return;
    float s = 0.f;
    for (int l = 0; l < LL; ++l) s += query[l * DD + d];
    qpool[d] = s * (1.f / LL);
}

// ---------------------------------------------------------------- K2b: qV = q @ V  (2D,)
__global__ __launch_bounds__(640) void k_qV(const float* __restrict__ qpool,
                                            const float* __restrict__ V,
                                            float* __restrict__ qV) {
    int k = threadIdx.x;
    if (k >= D2) return;
    float s = 0.f;
    for (int d = 0; d < DD; ++d) s += qpool[d] * V[d * D2 + k];
    qV[k] = s;
}

// ---------------------------------------------------------------- K2c: sig[n] = sigmoid(qV . ent[n] / sqrt(D))
__global__ __launch_bounds__(64) void k_gamma(const float* __restrict__ qV,
                                              const float* __restrict__ ent,
                                              float* __restrict__ sig) {
    int n = blockIdx.x, t = threadIdx.x;
    float s = 0.f;
    for (int k = t; k < D2; k += 64) s += qV[k] * ent[n * D2 + k];
    for (int off = 32; off; off >>= 1) s += __shfl_down(s, off);
    if (t == 0) sig[n] = sigmoidf_(s / DROOT);
}

// ---------------------------------------------------------------- K3: hidden = (sig*ent)@U.T + b ; a_i ; c_j
__global__ __launch_bounds__(256) void k_hidden(const float* __restrict__ ent,
                                                const float* __restrict__ sig,
                                                const float* __restrict__ U,
                                                const float* __restrict__ bvec,
                                                const float* __restrict__ W,
                                                float* __restrict__ hidden,
                                                float* __restrict__ a_i,
                                                float* __restrict__ c_j) {
    __shared__ float e_s[D2];
    __shared__ float r_s[2][4];
    int n = blockIdx.x, t = threadIdx.x;
    float sg = sig[n];
    for (int k = t; k < D2; k += 256) e_s[k] = ent[n * D2 + k] * sg;
    __syncthreads();
    float wa = 0.f, wc = 0.f;
    for (int d = t; d < DD; d += 256) {
        float s = bvec[d];
        const float* Ur = U + (size_t)d * D2;
        #pragma unroll 4
        for (int k = 0; k < D2; ++k) s += e_s[k] * Ur[k];
        hidden[n * DD + d] = s;
        wa += s * W[d];
        wc += s * W[DD + d];
    }
    for (int off = 32; off; off >>= 1) { wa += __shfl_down(wa, off); wc += __shfl_down(wc, off); }
    if ((t & 63) == 0) { r_s[0][t >> 6] = wa; r_s[1][t >> 6] = wc; }
    __syncthreads();
    if (t == 0) {
        float A = 0.f, C = 0.f;
        for (int w = 0; w < 4; ++w) { A += r_s[0][w]; C += r_s[1][w]; }
        a_i[n] = A; c_j[n] = C;
    }
}

// ---------------------------------------------------------------- K4: alphas = softmax(betas, axis=1)
__global__ __launch_bounds__(256) void k_alphas(const float* __restrict__ adj,
                                                const float* __restrict__ ai,
                                                const float* __restrict__ cj,
                                                float* __restrict__ alphas) {
    __shared__ float red[4];
    __shared__ float bc[2];
    int i = blockIdx.x, j = threadIdx.x;
    float beta = 0.f;
    if (adj[i * NN + j] > 0.f) {
        float v = ai[i] + cj[j];
        beta = (v > 0.f) ? v : 0.01f * v;   // leaky_relu, slope 0.01
    }
    float wm = beta;
    for (int off = 32; off; off >>= 1) wm = fmaxf(wm, __shfl_down(wm, off));
    if ((j & 63) == 0) red[j >> 6] = wm;
    __syncthreads();
    if (j == 0) {
        float m = red[0];
        for (int w = 1; w < 4; ++w) m = fmaxf(m, red[w]);
        bc[0] = m;
    }
    __syncthreads();
    float e = expf(beta - bc[0]);
    float ws_ = e;
    for (int off = 32; off; off >>= 1) ws_ += __shfl_down(ws_, off);
    __syncthreads();
    if ((j & 63) == 0) red[j >> 6] = ws_;
    __syncthreads();
    if (j == 0) bc[1] = 1.f / (red[0] + red[1] + red[2] + red[3]);
    __syncthreads();
    alphas[i * NN + j] = e * bc[1];
}

// ---------------------------------------------------------------- K5: E_t[i] = relu(sum_j adj[i,j]*alphas[j,i]*hidden[j])
__global__ __launch_bounds__(320) void k_Et(const float* __restrict__ adj,
                                            const float* __restrict__ alphas,
                                            const float* __restrict__ hidden,
                                            float* __restrict__ Et) {
    __shared__ float w_s[NN];
    int i = blockIdx.x, t = threadIdx.x;
    if (t < NN) w_s[t] = adj[i * NN + t] * alphas[t * NN + i];
    __syncthreads();
    if (t >= DD) return;
    float s = 0.f;
    for (int j = 0; j < NN; ++j) s += w_s[j] * hidden[j * DD + t];
    Et[i * DD + t] = fmaxf(s, 0.f);
}

// ---------------------------------------------------------------- K6: cq[l], ce[n]
__global__ __launch_bounds__(64) void k_cqce(const float* __restrict__ query,
                                             const float* __restrict__ Et,
                                             const float* __restrict__ w_att,
                                             const float* __restrict__ b_att,
                                             float* __restrict__ cq,
                                             float* __restrict__ ce) {
    int idx = blockIdx.x, t = threadIdx.x;
    float s = 0.f;
    if (idx < LL) {
        const float* src = query + idx * DD;
        for (int d = t; d < DD; d += 64) s += src[d] * w_att[d];
        for (int off = 32; off; off >>= 1) s += __shfl_down(s, off);
        if (t == 0) cq[idx] = s + b_att[0];
    } else {
        int n = idx - LL;
        const float* src = Et + n * DD;
        for (int d = t; d < DD; d += 64) s += src[d] * w_att[DD + d];
        for (int off = 32; off; off >>= 1) s += __shfl_down(s, off);
        if (t == 0) ce[n] = s + b_att[1];
    }
}

// ---------------------------------------------------------------- K7: S[l,n] + rowmax[l]
__global__ __launch_bounds__(256) void k_S(const float* __restrict__ query,
                                           const float* __restrict__ Et,
                                           const float* __restrict__ w_att,
                                           const float* __restrict__ b_att,
                                           const float* __restrict__ cq,
                                           const float* __restrict__ ce,
                                           float* __restrict__ S,
                                           float* __restrict__ rowmax) {
    __shared__ float qw[DD];
    __shared__ float red[4];
    int l = blockIdx.x, n = threadIdx.x;
    for (int d = n; d < DD; d += 256) qw[d] = query[l * DD + d] * w_att[2 * DD + d];
    __syncthreads();
    const float* e = Et + n * DD;
    float s = 0.f;
    for (int d = 0; d < DD; ++d) s += qw[d] * e[d];
    float val = cq[l] + ce[n] + s + b_att[2];
    S[l * NN + n] = val;
    float wm = val;
    for (int off = 32; off; off >>= 1) wm = fmaxf(wm, __shfl_down(wm, off));
    if ((n & 63) == 0) red[n >> 6] = wm;
    __syncthreads();
    if (n == 0) rowmax[l] = fmaxf(fmaxf(red[0], red[1]), fmaxf(red[2], red[3]));
}

// ---------------------------------------------------------------- K8: c2q = softmax(S,1) @ E_t
__global__ __launch_bounds__(256) void k_c2q(const float* __restrict__ S,
                                             const float* __restrict__ rowmax,
                                             const float* __restrict__ Et,
                                             float* __restrict__ c2q) {
    __shared__ float p[NN];
    __shared__ float red[4];
    __shared__ float inv;
    int l = blockIdx.x, t = threadIdx.x;
    float e = expf(S[l * NN + t] - rowmax[l]);
    float ws_ = e;
    for (int off = 32; off; off >>= 1) ws_ += __shfl_down(ws_, off);
    if ((t & 63) == 0) red[t >> 6] = ws_;
    __syncthreads();
    if (t == 0) inv = 1.f / (red[0] + red[1] + red[2] + red[3]);
    __syncthreads();
    p[t] = e * inv;
    __syncthreads();
    for (int d = t; d < DD; d += 256) {
        float s = 0.f;
        for (int j = 0; j < NN; ++j) s += p[j] * Et[j * DD + d];
        c2q[l * DD + d] = s;
    }
}

// ---------------------------------------------------------------- K9: q2c = softmax(rowmax) @ query
__global__ __launch_bounds__(320) void k_q2c(const float* __restrict__ rowmax,
                                             const float* __restrict__ query,
                                             float* __restrict__ q2c) {
    __shared__ float p[LL];
    __shared__ float red[5];
    __shared__ float bc[2];
    int t = threadIdx.x;
    float v = (t < LL) ? rowmax[t] : -1e30f;
    float wm = v;
    for (int off = 32; off; off >>= 1) wm = fmaxf(wm, __shfl_down(wm, off));
    if ((t & 63) == 0) red[t >> 6] = wm;
    __syncthreads();
    if (t == 0) {
        float m = red[0];
        for (int w = 1; w < 5; ++w) m = fmaxf(m, red[w]);
        bc[0] = m;
    }
    __syncthreads();
    float e = (t < LL) ? expf(v - bc[0]) : 0.f;
    float ws_ = e;
    for (int off = 32; off; off >>= 1) ws_ += __shfl_down(ws_, off);
    __syncthreads();
    if ((t & 63) == 0) red[t >> 6] = ws_;
    __syncthreads();
    if (t == 0) {
        float s = 0.f;
        for (int w = 0; w < 5; ++w) s += red[w];
        bc[1] = 1.f / s;
    }
    __syncthreads();
    if (t < LL) p[t] = e * bc[1];
    __syncthreads();
    if (t < DD) {
        float s = 0.f;
        for (int l = 0; l < LL; ++l) s += p[l] * query[l * DD + t];
        q2c[t] = s;
    }
}

// ---------------------------------------------------------------- K10: qry_out = x @ W_red.T + b_red
__global__ __launch_bounds__(320) void k_red(const float* __restrict__ query,
                                             const float* __restrict__ c2q,
                                             const float* __restrict__ q2c,
                                             const float* __restrict__ Wred,
                                             const float* __restrict__ bred,
                                             float* __restrict__ outq) {
    __shared__ float xs[D4];
    int l = blockIdx.x, t = threadIdx.x;
    for (int d = t; d < DD; d += 320) {
        float q = query[l * DD + d], c = c2q[l * DD + d];
        xs[d] = q; xs[DD + d] = c; xs[2 * DD + d] = q * c; xs[3 * DD + d] = q * q2c[d];
    }
    __syncthreads();
    if (t < DD) {
        float s = bred[t];
        const float* wr = Wred + (size_t)t * D4;
        #pragma unroll 4
        for (int k = 0; k < D4; ++k) s += xs[k] * wr[k];
        outq[l * DD + t] = s;
    }
}

// ---------------------------------------------------------------- K11: xbuf = [context | bin_M @ E_t]
__global__ __launch_bounds__(320) void k_xbuf(const float* __restrict__ ctx,
                                              const float* __restrict__ binM,
                                              const float* __restrict__ Et,
                                              float* __restrict__ xbuf) {
    int m = blockIdx.x, d = threadIdx.x;
    if (d >= DD) return;
    xbuf[m * D2 + d] = ctx[m * DD + d];
    float s = 0.f;
    for (int n = 0; n < NN; ++n) {
        float b = binM[m * NN + n];      // uniform across threads
        if (b != 0.f) s += Et[n * DD + d];
    }
    xbuf[m * D2 + DD + d] = s;
}

// ---------------------------------------------------------------- K12: gates = xbuf @ W_ih.T   (2048 x 1200, K=600)
#define BM 64
#define BG 64
#define BK 16
__global__ __launch_bounds__(256) void k_gemm_gates(const float* __restrict__ X,
                                                    const float* __restrict__ Wih,
                                                    float* __restrict__ gates) {
    __shared__ float Xs[BK][BM];
    __shared__ float Ws[BK][BG];
    int m0 = blockIdx.x * BM;
    int g0 = blockIdx.y * BG;
    int tid = threadIdx.x;
    int tx = tid & 15, ty = tid >> 4;
    float acc[4][4] = {};
    for (int k0 = 0; k0 < D2; k0 += BK) {
        #pragma unroll
        for (int rep = 0; rep < 4; ++rep) {
            int idx = rep * 256 + tid;      // 0..1023
            int i = idx >> 4, kk = idx & 15;
            int k = k0 + kk;
            Xs[kk][i] = (k < D2) ? X[(size_t)(m0 + i) * D2 + k] : 0.f;
            int gg = g0 + i;
            Ws[kk][i] = (k < D2 && gg < D4) ? Wih[(size_t)gg * D2 + k] : 0.f;
        }
        __syncthreads();
        #pragma unroll
        for (int kk = 0; kk < BK; ++kk) {
            float a[4], b[4];
            #pragma unroll
            for (int u = 0; u < 4; ++u) a[u] = Xs[kk][ty * 4 + u];
            #pragma unroll
            for (int u = 0; u < 4; ++u) b[u] = Ws[kk][tx * 4 + u];
            #pragma unroll
            for (int ii = 0; ii < 4; ++ii)
                #pragma unroll
                for (int jj = 0; jj < 4; ++jj) acc[ii][jj] += a[ii] * b[jj];
        }
        __syncthreads();
    }
    #pragma unroll
    for (int ii = 0; ii < 4; ++ii) {
        int m = m0 + ty * 4 + ii;
        #pragma unroll
        for (int jj = 0; jj < 4; ++jj) {
            int g = g0 + tx * 4 + jj;
            if (g < D4) gates[(size_t)m * D4 + g] = acc[ii][jj];
        }
    }
}

// ---------------------------------------------------------------- K13: LSTM-cell epilogue
__global__ __launch_bounds__(320) void k_lstm(const float* __restrict__ gates,
                                              const float* __restrict__ bih,
                                              const float* __restrict__ bhh,
                                              float* __restrict__ outc) {
    int m = blockIdx.x, d = threadIdx.x;
    if (d >= DD) return;
    const float* g = gates + (size_t)m * D4;
    float gi = g[d]          + bih[d]          + bhh[d];
    float gg = g[2 * DD + d] + bih[2 * DD + d] + bhh[2 * DD + d];
    float go = g[3 * DD + d] + bih[3 * DD + d] + bhh[3 * DD + d];
    float c = sigmoidf_(gi) * tanhf(gg);
    outc[m * DD + d] = sigmoidf_(go) * tanhf(c);
}

// ================================================================ launch
extern "C" void kernel_launch(void* const* d_in, const int* in_sizes, int n_in,
                              void* d_out, int out_size, void* d_ws, size_t ws_size,
                              hipStream_t stream) {
    const float* context = (const float*)d_in[0];
    const float* query   = (const float*)d_in[1];
    const float* binM    = (const float*)d_in[2];
    const float* adj     = (const float*)d_in[3];
    const float* V       = (const float*)d_in[4];
    const float* U       = (const float*)d_in[5];
    const float* bvec    = (const float*)d_in[6];
    const float* W       = (const float*)d_in[7];
    const float* w_att   = (const float*)d_in[8];
    const float* b_att   = (const float*)d_in[9];
    const float* W_red   = (const float*)d_in[10];
    const float* b_red   = (const float*)d_in[11];
    const float* W_ih    = (const float*)d_in[12];
    const float* b_ih    = (const float*)d_in[13];
    const float* b_hh    = (const float*)d_in[14];
    // passes == 1 (setup constant)

    float* ws = (float*)d_ws;
    float* ent    = ws;                 // 153600
    float* qpool  = ent    + 153600;    // 304
    float* qV     = qpool  + 304;       // 608
    float* sig    = qV     + 608;       // 256
    float* hidden = sig    + 256;       // 76800
    float* a_i    = hidden + 76800;     // 256
    float* c_j    = a_i    + 256;       // 256
    float* alphas = c_j    + 256;       // 65536
    float* Et     = alphas + 65536;     // 76800
    float* cq     = Et     + 76800;     // 128
    float* ce     = cq     + 128;       // 256
    float* Smat   = ce     + 256;       // 32768
    float* rmax   = Smat   + 32768;     // 128
    float* c2q    = rmax   + 128;       // 38400
    float* q2c    = c2q    + 38400;     // 304
    float* xbuf   = q2c    + 304;       // 1228800
    float* gates  = xbuf   + 1228800;   // 2457600

    float* outc = (float*)d_out;            // ctx: (M, D)
    float* outq = (float*)d_out + MM * DD;  // qry: (L, D)

    hipLaunchKernelGGL(k_tok2ent, dim3(NN), dim3(320), 0, stream, context, binM, ent);
    hipLaunchKernelGGL(k_qpool,   dim3(1),  dim3(320), 0, stream, query, qpool);
    hipLaunchKernelGGL(k_qV,      dim3(1),  dim3(640), 0, stream, qpool, V, qV);
    hipLaunchKernelGGL(k_gamma,   dim3(NN), dim3(64),  0, stream, qV, ent, sig);
    hipLaunchKernelGGL(k_hidden,  dim3(NN), dim3(256), 0, stream, ent, sig, U, bvec, W, hidden, a_i, c_j);
    hipLaunchKernelGGL(k_alphas,  dim3(NN), dim3(256), 0, stream, adj, a_i, c_j, alphas);
    hipLaunchKernelGGL(k_Et,      dim3(NN), dim3(320), 0, stream, adj, alphas, hidden, Et);
    hipLaunchKernelGGL(k_cqce,    dim3(LL + NN), dim3(64), 0, stream, query, Et, w_att, b_att, cq, ce);
    hipLaunchKernelGGL(k_S,       dim3(LL), dim3(256), 0, stream, query, Et, w_att, b_att, cq, ce, Smat, rmax);
    hipLaunchKernelGGL(k_c2q,     dim3(LL), dim3(256), 0, stream, Smat, rmax, Et, c2q);
    hipLaunchKernelGGL(k_q2c,     dim3(1),  dim3(320), 0, stream, rmax, query, q2c);
    hipLaunchKernelGGL(k_red,     dim3(LL), dim3(320), 0, stream, query, c2q, q2c, W_red, b_red, outq);
    hipLaunchKernelGGL(k_xbuf,    dim3(MM), dim3(320), 0, stream, context, binM, Et, xbuf);
    hipLaunchKernelGGL(k_gemm_gates, dim3(MM / BM, (D4 + BG - 1) / BG), dim3(256), 0, stream, xbuf, W_ih, gates);
    hipLaunchKernelGGL(k_lstm,    dim3(MM), dim3(320), 0, stream, gates, b_ih, b_hh, outc);
}

// Round 2
// 337.948 us; speedup vs baseline: 2.5082x; 2.5082x over previous
//
#include <hip/hip_runtime.h>
#include <hip/hip_bf16.h>
#include <math.h>

// Problem constants
#define MM 2048   // context length
#define NN 256    // entities
#define LL 128    // query length
#define DD 300    // d2
#define D2 600    // 2*D
#define D4 1200   // 4*D
#define DROOT 17.320508075688775f

__device__ __forceinline__ float sigmoidf_(float x) { return 1.f / (1.f + expf(-x)); }

// ---------------------------------------------------------------- K1: tok2ent
// Two-phase: (A) parallel scan of binM column + deterministic ballot-compaction
// of member token indices into LDS (ascending m order -> same float-add order
// as reference); (B) coalesced accumulation of ~41 ctx rows, parallel over d.
#define T2E_T 512
__global__ __launch_bounds__(T2E_T) void k_tok2ent(const float* __restrict__ ctx,
                                                   const float* __restrict__ binM,
                                                   float* __restrict__ ent) {
    __shared__ int lst[MM];          // member token indices (worst case all)
    __shared__ int wcnt[T2E_T / 64];
    int n = blockIdx.x, t = threadIdx.x;
    int wave = t >> 6, lane = t & 63;
    int total = 0;
    // ---- phase A: compaction, chunk by chunk (2048 = 4 * 512, no bounds check)
    for (int c = 0; c < MM; c += T2E_T) {
        int m = c + t;
        float b = binM[(size_t)m * NN + n];
        unsigned long long mask = __ballot(b != 0.f);
        int prefix = __popcll(mask & ((1ull << lane) - 1ull));
        if (lane == 0) wcnt[wave] = (int)__popcll(mask);
        __syncthreads();
        int wbase = total;
        for (int w = 0; w < wave; ++w) wbase += wcnt[w];
        if (b != 0.f) lst[wbase + prefix] = m;
        int chunk_total = 0;
        for (int w = 0; w < T2E_T / 64; ++w) chunk_total += wcnt[w];
        total += chunk_total;
        __syncthreads();
    }
    // ---- phase B: accumulate member rows (coalesced over d)
    if (t < DD) {
        float sum = 0.f, mx = 0.f;   // max includes the zeros of non-members
        int i = 0;
        for (; i + 4 <= total; i += 4) {
            int m0 = lst[i], m1 = lst[i + 1], m2 = lst[i + 2], m3 = lst[i + 3];
            float v0 = ctx[(size_t)m0 * DD + t];
            float v1 = ctx[(size_t)m1 * DD + t];
            float v2 = ctx[(size_t)m2 * DD + t];
            float v3 = ctx[(size_t)m3 * DD + t];
            sum += v0; mx = fmaxf(mx, v0);
            sum += v1; mx = fmaxf(mx, v1);
            sum += v2; mx = fmaxf(mx, v2);
            sum += v3; mx = fmaxf(mx, v3);
        }
        for (; i < total; ++i) {
            float v = ctx[(size_t)lst[i] * DD + t];
            sum += v; mx = fmaxf(mx, v);
        }
        ent[n * D2 + t]      = sum * (1.f / MM);
        ent[n * D2 + DD + t] = mx;
    }
}

// ---------------------------------------------------------------- K2a: query mean pool
__global__ __launch_bounds__(320) void k_qpool(const float* __restrict__ query,
                                               float* __restrict__ qpool) {
    int d = threadIdx.x;
    if (d >= DD) return;
    float s = 0.f;
    for (int l = 0; l < LL; ++l) s += query[l * DD + d];
    qpool[d] = s * (1.f / LL);
}

// ---------------------------------------------------------------- K2b: qV = q @ V  (2D,)
__global__ __launch_bounds__(640) void k_qV(const float* __restrict__ qpool,
                                            const float* __restrict__ V,
                                            float* __restrict__ qV) {
    int k = threadIdx.x;
    if (k >= D2) return;
    float s = 0.f;
    for (int d = 0; d < DD; ++d) s += qpool[d] * V[d * D2 + k];
    qV[k] = s;
}

// ---------------------------------------------------------------- K2c: sig[n] = sigmoid(qV . ent[n] / sqrt(D))
__global__ __launch_bounds__(64) void k_gamma(const float* __restrict__ qV,
                                              const float* __restrict__ ent,
                                              float* __restrict__ sig) {
    int n = blockIdx.x, t = threadIdx.x;
    float s = 0.f;
    for (int k = t; k < D2; k += 64) s += qV[k] * ent[n * D2 + k];
    for (int off = 32; off; off >>= 1) s += __shfl_down(s, off);
    if (t == 0) sig[n] = sigmoidf_(s / DROOT);
}

// ---------------------------------------------------------------- K3: hidden = (sig*ent)@U.T + b ; a_i ; c_j
__global__ __launch_bounds__(256) void k_hidden(const float* __restrict__ ent,
                                                const float* __restrict__ sig,
                                                const float* __restrict__ U,
                                                const float* __restrict__ bvec,
                                                const float* __restrict__ W,
                                                float* __restrict__ hidden,
                                                float* __restrict__ a_i,
                                                float* __restrict__ c_j) {
    __shared__ float e_s[D2];
    __shared__ float r_s[2][4];
    int n = blockIdx.x, t = threadIdx.x;
    float sg = sig[n];
    for (int k = t; k < D2; k += 256) e_s[k] = ent[n * D2 + k] * sg;
    __syncthreads();
    float wa = 0.f, wc = 0.f;
    for (int d = t; d < DD; d += 256) {
        float s = bvec[d];
        const float* Ur = U + (size_t)d * D2;
        #pragma unroll 4
        for (int k = 0; k < D2; ++k) s += e_s[k] * Ur[k];
        hidden[n * DD + d] = s;
        wa += s * W[d];
        wc += s * W[DD + d];
    }
    for (int off = 32; off; off >>= 1) { wa += __shfl_down(wa, off); wc += __shfl_down(wc, off); }
    if ((t & 63) == 0) { r_s[0][t >> 6] = wa; r_s[1][t >> 6] = wc; }
    __syncthreads();
    if (t == 0) {
        float A = 0.f, C = 0.f;
        for (int w = 0; w < 4; ++w) { A += r_s[0][w]; C += r_s[1][w]; }
        a_i[n] = A; c_j[n] = C;
    }
}

// ---------------------------------------------------------------- K4: alphas = softmax(betas, axis=1)
__global__ __launch_bounds__(256) void k_alphas(const float* __restrict__ adj,
                                                const float* __restrict__ ai,
                                                const float* __restrict__ cj,
                                                float* __restrict__ alphas) {
    __shared__ float red[4];
    __shared__ float bc[2];
    int i = blockIdx.x, j = threadIdx.x;
    float beta = 0.f;
    if (adj[i * NN + j] > 0.f) {
        float v = ai[i] + cj[j];
        beta = (v > 0.f) ? v : 0.01f * v;   // leaky_relu, slope 0.01
    }
    float wm = beta;
    for (int off = 32; off; off >>= 1) wm = fmaxf(wm, __shfl_down(wm, off));
    if ((j & 63) == 0) red[j >> 6] = wm;
    __syncthreads();
    if (j == 0) {
        float m = red[0];
        for (int w = 1; w < 4; ++w) m = fmaxf(m, red[w]);
        bc[0] = m;
    }
    __syncthreads();
    float e = expf(beta - bc[0]);
    float ws_ = e;
    for (int off = 32; off; off >>= 1) ws_ += __shfl_down(ws_, off);
    __syncthreads();
    if ((j & 63) == 0) red[j >> 6] = ws_;
    __syncthreads();
    if (j == 0) bc[1] = 1.f / (red[0] + red[1] + red[2] + red[3]);
    __syncthreads();
    alphas[i * NN + j] = e * bc[1];
}

// ---------------------------------------------------------------- K5: E_t[i] = relu(sum_j adj[i,j]*alphas[j,i]*hidden[j])
__global__ __launch_bounds__(320) void k_Et(const float* __restrict__ adj,
                                            const float* __restrict__ alphas,
                                            const float* __restrict__ hidden,
                                            float* __restrict__ Et) {
    __shared__ float w_s[NN];
    int i = blockIdx.x, t = threadIdx.x;
    if (t < NN) w_s[t] = adj[i * NN + t] * alphas[t * NN + i];
    __syncthreads();
    if (t >= DD) return;
    float s = 0.f;
    for (int j = 0; j < NN; ++j) s += w_s[j] * hidden[j * DD + t];
    Et[i * DD + t] = fmaxf(s, 0.f);
}

// ---------------------------------------------------------------- K6: cq[l], ce[n]
__global__ __launch_bounds__(64) void k_cqce(const float* __restrict__ query,
                                             const float* __restrict__ Et,
                                             const float* __restrict__ w_att,
                                             const float* __restrict__ b_att,
                                             float* __restrict__ cq,
                                             float* __restrict__ ce) {
    int idx = blockIdx.x, t = threadIdx.x;
    float s = 0.f;
    if (idx < LL) {
        const float* src = query + idx * DD;
        for (int d = t; d < DD; d += 64) s += src[d] * w_att[d];
        for (int off = 32; off; off >>= 1) s += __shfl_down(s, off);
        if (t == 0) cq[idx] = s + b_att[0];
    } else {
        int n = idx - LL;
        const float* src = Et + n * DD;
        for (int d = t; d < DD; d += 64) s += src[d] * w_att[DD + d];
        for (int off = 32; off; off >>= 1) s += __shfl_down(s, off);
        if (t == 0) ce[n] = s + b_att[1];
    }
}

// ---------------------------------------------------------------- K7: S[l,n] + rowmax[l]
__global__ __launch_bounds__(256) void k_S(const float* __restrict__ query,
                                           const float* __restrict__ Et,
                                           const float* __restrict__ w_att,
                                           const float* __restrict__ b_att,
                                           const float* __restrict__ cq,
                                           const float* __restrict__ ce,
                                           float* __restrict__ S,
                                           float* __restrict__ rowmax) {
    __shared__ float qw[DD];
    __shared__ float red[4];
    int l = blockIdx.x, n = threadIdx.x;
    for (int d = n; d < DD; d += 256) qw[d] = query[l * DD + d] * w_att[2 * DD + d];
    __syncthreads();
    const float* e = Et + n * DD;
    float s = 0.f;
    for (int d = 0; d < DD; ++d) s += qw[d] * e[d];
    float val = cq[l] + ce[n] + s + b_att[2];
    S[l * NN + n] = val;
    float wm = val;
    for (int off = 32; off; off >>= 1) wm = fmaxf(wm, __shfl_down(wm, off));
    if ((n & 63) == 0) red[n >> 6] = wm;
    __syncthreads();
    if (n == 0) rowmax[l] = fmaxf(fmaxf(red[0], red[1]), fmaxf(red[2], red[3]));
}

// ---------------------------------------------------------------- K8: c2q = softmax(S,1) @ E_t
__global__ __launch_bounds__(256) void k_c2q(const float* __restrict__ S,
                                             const float* __restrict__ rowmax,
                                             const float* __restrict__ Et,
                                             float* __restrict__ c2q) {
    __shared__ float p[NN];
    __shared__ float red[4];
    __shared__ float inv;
    int l = blockIdx.x, t = threadIdx.x;
    float e = expf(S[l * NN + t] - rowmax[l]);
    float ws_ = e;
    for (int off = 32; off; off >>= 1) ws_ += __shfl_down(ws_, off);
    if ((t & 63) == 0) red[t >> 6] = ws_;
    __syncthreads();
    if (t == 0) inv = 1.f / (red[0] + red[1] + red[2] + red[3]);
    __syncthreads();
    p[t] = e * inv;
    __syncthreads();
    for (int d = t; d < DD; d += 256) {
        float s = 0.f;
        for (int j = 0; j < NN; ++j) s += p[j] * Et[j * DD + d];
        c2q[l * DD + d] = s;
    }
}

// ---------------------------------------------------------------- K9: q2c = softmax(rowmax) @ query
__global__ __launch_bounds__(320) void k_q2c(const float* __restrict__ rowmax,
                                             const float* __restrict__ query,
                                             float* __restrict__ q2c) {
    __shared__ float p[LL];
    __shared__ float red[5];
    __shared__ float bc[2];
    int t = threadIdx.x;
    float v = (t < LL) ? rowmax[t] : -1e30f;
    float wm = v;
    for (int off = 32; off; off >>= 1) wm = fmaxf(wm, __shfl_down(wm, off));
    if ((t & 63) == 0) red[t >> 6] = wm;
    __syncthreads();
    if (t == 0) {
        float m = red[0];
        for (int w = 1; w < 5; ++w) m = fmaxf(m, red[w]);
        bc[0] = m;
    }
    __syncthreads();
    float e = (t < LL) ? expf(v - bc[0]) : 0.f;
    float ws_ = e;
    for (int off = 32; off; off >>= 1) ws_ += __shfl_down(ws_, off);
    __syncthreads();
    if ((t & 63) == 0) red[t >> 6] = ws_;
    __syncthreads();
    if (t == 0) {
        float s = 0.f;
        for (int w = 0; w < 5; ++w) s += red[w];
        bc[1] = 1.f / s;
    }
    __syncthreads();
    if (t < LL) p[t] = e * bc[1];
    __syncthreads();
    if (t < DD) {
        float s = 0.f;
        for (int l = 0; l < LL; ++l) s += p[l] * query[l * DD + t];
        q2c[t] = s;
    }
}

// ---------------------------------------------------------------- K10: qry_out = x @ W_red.T + b_red
__global__ __launch_bounds__(320) void k_red(const float* __restrict__ query,
                                             const float* __restrict__ c2q,
                                             const float* __restrict__ q2c,
                                             const float* __restrict__ Wred,
                                             const float* __restrict__ bred,
                                             float* __restrict__ outq) {
    __shared__ float xs[D4];
    int l = blockIdx.x, t = threadIdx.x;
    for (int d = t; d < DD; d += 320) {
        float q = query[l * DD + d], c = c2q[l * DD + d];
        xs[d] = q; xs[DD + d] = c; xs[2 * DD + d] = q * c; xs[3 * DD + d] = q * q2c[d];
    }
    __syncthreads();
    if (t < DD) {
        float s = bred[t];
        const float* wr = Wred + (size_t)t * D4;
        #pragma unroll 4
        for (int k = 0; k < D4; ++k) s += xs[k] * wr[k];
        outq[l * DD + t] = s;
    }
}

// ---------------------------------------------------------------- K11: xbuf = [context | bin_M @ E_t]
// binM row staged through ballot-compaction (ascending n order = reference sum order).
__global__ __launch_bounds__(320) void k_xbuf(const float* __restrict__ ctx,
                                              const float* __restrict__ binM,
                                              const float* __restrict__ Et,
                                              float* __restrict__ xbuf) {
    __shared__ int lst[NN];
    __shared__ int wcnt[5];
    __shared__ int total_s;
    int m = blockIdx.x, t = threadIdx.x;
    int wave = t >> 6, lane = t & 63;
    float b = (t < NN) ? binM[(size_t)m * NN + t] : 0.f;
    unsigned long long mask = __ballot(b != 0.f);
    int prefix = __popcll(mask & ((1ull << lane) - 1ull));
    if (lane == 0) wcnt[wave] = (int)__popcll(mask);
    __syncthreads();
    int wbase = 0;
    for (int w = 0; w < wave; ++w) wbase += wcnt[w];
    if (b != 0.f) lst[wbase + prefix] = t;
    if (t == 0) total_s = wcnt[0] + wcnt[1] + wcnt[2] + wcnt[3] + wcnt[4];
    __syncthreads();
    int total = total_s;
    if (t >= DD) return;
    xbuf[(size_t)m * D2 + t] = ctx[(size_t)m * DD + t];
    float s = 0.f;
    for (int i = 0; i < total; ++i) s += Et[(size_t)lst[i] * DD + t];
    xbuf[(size_t)m * D2 + DD + t] = s;
}

// ---------------------------------------------------------------- K12: gates = xbuf @ W_ih.T   (2048 x 1200, K=600)
#define BM 64
#define BG 64
#define BK 16
__global__ __launch_bounds__(256) void k_gemm_gates(const float* __restrict__ X,
                                                    const float* __restrict__ Wih,
                                                    float* __restrict__ gates) {
    __shared__ float Xs[BK][BM];
    __shared__ float Ws[BK][BG];
    int m0 = blockIdx.x * BM;
    int g0 = blockIdx.y * BG;
    int tid = threadIdx.x;
    int tx = tid & 15, ty = tid >> 4;
    float acc[4][4] = {};
    for (int k0 = 0; k0 < D2; k0 += BK) {
        #pragma unroll
        for (int rep = 0; rep < 4; ++rep) {
            int idx = rep * 256 + tid;      // 0..1023
            int i = idx >> 4, kk = idx & 15;
            int k = k0 + kk;
            Xs[kk][i] = (k < D2) ? X[(size_t)(m0 + i) * D2 + k] : 0.f;
            int gg = g0 + i;
            Ws[kk][i] = (k < D2 && gg < D4) ? Wih[(size_t)gg * D2 + k] : 0.f;
        }
        __syncthreads();
        #pragma unroll
        for (int kk = 0; kk < BK; ++kk) {
            float a[4], b2[4];
            #pragma unroll
            for (int u = 0; u < 4; ++u) a[u] = Xs[kk][ty * 4 + u];
            #pragma unroll
            for (int u = 0; u < 4; ++u) b2[u] = Ws[kk][tx * 4 + u];
            #pragma unroll
            for (int ii = 0; ii < 4; ++ii)
                #pragma unroll
                for (int jj = 0; jj < 4; ++jj) acc[ii][jj] += a[ii] * b2[jj];
        }
        __syncthreads();
    }
    #pragma unroll
    for (int ii = 0; ii < 4; ++ii) {
        int m = m0 + ty * 4 + ii;
        #pragma unroll
        for (int jj = 0; jj < 4; ++jj) {
            int g = g0 + tx * 4 + jj;
            if (g < D4) gates[(size_t)m * D4 + g] = acc[ii][jj];
        }
    }
}

// ---------------------------------------------------------------- K13: LSTM-cell epilogue
__global__ __launch_bounds__(320) void k_lstm(const float* __restrict__ gates,
                                              const float* __restrict__ bih,
                                              const float* __restrict__ bhh,
                                              float* __restrict__ outc) {
    int m = blockIdx.x, d = threadIdx.x;
    if (d >= DD) return;
    const float* g = gates + (size_t)m * D4;
    float gi = g[d]          + bih[d]          + bhh[d];
    float gg = g[2 * DD + d] + bih[2 * DD + d] + bhh[2 * DD + d];
    float go = g[3 * DD + d] + bih[3 * DD + d] + bhh[3 * DD + d];
    float c = sigmoidf_(gi) * tanhf(gg);
    outc[m * DD + d] = sigmoidf_(go) * tanhf(c);
}

// ================================================================ launch
extern "C" void kernel_launch(void* const* d_in, const int* in_sizes, int n_in,
                              void* d_out, int out_size, void* d_ws, size_t ws_size,
                              hipStream_t stream) {
    const float* context = (const float*)d_in[0];
    const float* query   = (const float*)d_in[1];
    const float* binM    = (const float*)d_in[2];
    const float* adj     = (const float*)d_in[3];
    const float* V       = (const float*)d_in[4];
    const float* U       = (const float*)d_in[5];
    const float* bvec    = (const float*)d_in[6];
    const float* W       = (const float*)d_in[7];
    const float* w_att   = (const float*)d_in[8];
    const float* b_att   = (const float*)d_in[9];
    const float* W_red   = (const float*)d_in[10];
    const float* b_red   = (const float*)d_in[11];
    const float* W_ih    = (const float*)d_in[12];
    const float* b_ih    = (const float*)d_in[13];
    const float* b_hh    = (const float*)d_in[14];
    // passes == 1 (setup constant)

    float* ws = (float*)d_ws;
    float* ent    = ws;                 // 153600
    float* qpool  = ent    + 153600;    // 304
    float* qV     = qpool  + 304;       // 608
    float* sig    = qV     + 608;       // 256
    float* hidden = sig    + 256;       // 76800
    float* a_i    = hidden + 76800;     // 256
    float* c_j    = a_i    + 256;       // 256
    float* alphas = c_j    + 256;       // 65536
    float* Et     = alphas + 65536;     // 76800
    float* cq     = Et     + 76800;     // 128
    float* ce     = cq     + 128;       // 256
    float* Smat   = ce     + 256;       // 32768
    float* rmax   = Smat   + 32768;     // 128
    float* c2q    = rmax   + 128;       // 38400
    float* q2c    = c2q    + 38400;     // 304
    float* xbuf   = q2c    + 304;       // 1228800
    float* gates  = xbuf   + 1228800;   // 2457600

    float* outc = (float*)d_out;            // ctx: (M, D)
    float* outq = (float*)d_out + MM * DD;  // qry: (L, D)

    hipLaunchKernelGGL(k_tok2ent, dim3(NN), dim3(T2E_T), 0, stream, context, binM, ent);
    hipLaunchKernelGGL(k_qpool,   dim3(1),  dim3(320), 0, stream, query, qpool);
    hipLaunchKernelGGL(k_qV,      dim3(1),  dim3(640), 0, stream, qpool, V, qV);
    hipLaunchKernelGGL(k_gamma,   dim3(NN), dim3(64),  0, stream, qV, ent, sig);
    hipLaunchKernelGGL(k_hidden,  dim3(NN), dim3(256), 0, stream, ent, sig, U, bvec, W, hidden, a_i, c_j);
    hipLaunchKernelGGL(k_alphas,  dim3(NN), dim3(256), 0, stream, adj, a_i, c_j, alphas);
    hipLaunchKernelGGL(k_Et,      dim3(NN), dim3(320), 0, stream, adj, alphas, hidden, Et);
    hipLaunchKernelGGL(k_cqce,    dim3(LL + NN), dim3(64), 0, stream, query, Et, w_att, b_att, cq, ce);
    hipLaunchKernelGGL(k_S,       dim3(LL), dim3(256), 0, stream, query, Et, w_att, b_att, cq, ce, Smat, rmax);
    hipLaunchKernelGGL(k_c2q,     dim3(LL), dim3(256), 0, stream, Smat, rmax, Et, c2q);
    hipLaunchKernelGGL(k_q2c,     dim3(1),  dim3(320), 0, stream, rmax, query, q2c);
    hipLaunchKernelGGL(k_red,     dim3(LL), dim3(320), 0, stream, query, c2q, q2c, W_red, b_red, outq);
    hipLaunchKernelGGL(k_xbuf,    dim3(MM), dim3(320), 0, stream, context, binM, Et, xbuf);
    hipLaunchKernelGGL(k_gemm_gates, dim3(MM / BM, (D4 + BG - 1) / BG), dim3(256), 0, stream, xbuf, W_ih, gates);
    hipLaunchKernelGGL(k_lstm,    dim3(MM), dim3(320), 0, stream, gates, b_ih, b_hh, outc);
}

// Round 3
// 229.748 us; speedup vs baseline: 3.6895x; 1.4710x over previous
//
#include <hip/hip_runtime.h>
#include <hip/hip_bf16.h>
#include <math.h>

// Problem constants
#define MM 2048   // context length
#define NN 256    // entities
#define LL 128    // query length
#define DD 300    // d2
#define D2 600    // 2*D
#define D4 1200   // 4*D
#define DROOT 17.320508075688775f

// GEMM geometry (gates = X @ Wsel^T), bf16 MFMA
#define KP 608    // K = 600 padded to 608 (19 * 32)
#define NP 960    // N = 900 (i,g,o gates) padded to 960
#define GM 64
#define GN 64
#define GK 32

typedef __attribute__((ext_vector_type(8))) short bf16x8;
typedef __attribute__((ext_vector_type(4))) float f32x4;

__device__ __forceinline__ float sigmoidf_(float x) { return 1.f / (1.f + expf(-x)); }

__device__ __forceinline__ ushort f2bf(float v) {
    union { float f; unsigned u; } x; x.f = v;
    unsigned r = x.u + 0x7fffu + ((x.u >> 16) & 1u);   // round-nearest-even
    return (ushort)(r >> 16);
}

// ---------------------------------------------------------------- K0: W_ih -> bf16, rows reordered [i | g | o], K padded
__global__ __launch_bounds__(256) void k_convW(const float* __restrict__ Wih,
                                               ushort* __restrict__ Wb) {
    int r = blockIdx.x;                       // 0..959
    int src = (r < DD) ? r : r + DD;          // i: r ; g: 600+(r-300)=r+300 ; o: 900+(r-600)=r+300
    bool valid = (r < 3 * DD);
    for (int e = threadIdx.x; e < KP; e += 256) {
        float v = (valid && e < D2) ? Wih[(size_t)src * D2 + e] : 0.f;
        Wb[(size_t)r * KP + e] = f2bf(v);
    }
}

// ---------------------------------------------------------------- K1: tok2ent (ballot-compaction + coalesced accumulate)
#define T2E_T 512
__global__ __launch_bounds__(T2E_T) void k_tok2ent(const float* __restrict__ ctx,
                                                   const float* __restrict__ binM,
                                                   float* __restrict__ ent) {
    __shared__ int lst[MM];
    __shared__ int wcnt[T2E_T / 64];
    int n = blockIdx.x, t = threadIdx.x;
    int wave = t >> 6, lane = t & 63;
    int total = 0;
    for (int c = 0; c < MM; c += T2E_T) {
        int m = c + t;
        float b = binM[(size_t)m * NN + n];
        unsigned long long mask = __ballot(b != 0.f);
        int prefix = __popcll(mask & ((1ull << lane) - 1ull));
        if (lane == 0) wcnt[wave] = (int)__popcll(mask);
        __syncthreads();
        int wbase = total;
        for (int w = 0; w < wave; ++w) wbase += wcnt[w];
        if (b != 0.f) lst[wbase + prefix] = m;
        int chunk_total = 0;
        for (int w = 0; w < T2E_T / 64; ++w) chunk_total += wcnt[w];
        total += chunk_total;
        __syncthreads();
    }
    if (t < DD) {
        float sum = 0.f, mx = 0.f;    // max includes zeros of non-members
        int i = 0;
        for (; i + 4 <= total; i += 4) {
            float v0 = ctx[(size_t)lst[i] * DD + t];
            float v1 = ctx[(size_t)lst[i + 1] * DD + t];
            float v2 = ctx[(size_t)lst[i + 2] * DD + t];
            float v3 = ctx[(size_t)lst[i + 3] * DD + t];
            sum += v0; mx = fmaxf(mx, v0);
            sum += v1; mx = fmaxf(mx, v1);
            sum += v2; mx = fmaxf(mx, v2);
            sum += v3; mx = fmaxf(mx, v3);
        }
        for (; i < total; ++i) {
            float v = ctx[(size_t)lst[i] * DD + t];
            sum += v; mx = fmaxf(mx, v);
        }
        ent[n * D2 + t]      = sum * (1.f / MM);
        ent[n * D2 + DD + t] = mx;
    }
}

// ---------------------------------------------------------------- K2: qprep = mean-pool query then @V  (1 block)
__global__ __launch_bounds__(640) void k_qprep(const float* __restrict__ query,
                                               const float* __restrict__ V,
                                               float* __restrict__ qV) {
    __shared__ float qp[DD];
    int t = threadIdx.x;
    if (t < DD) {
        float s = 0.f;
        for (int l = 0; l < LL; ++l) s += query[l * DD + t];
        qp[t] = s * (1.f / LL);
    }
    __syncthreads();
    if (t < D2) {
        float s = 0.f;
        for (int d = 0; d < DD; ++d) s += qp[d] * V[d * D2 + t];
        qV[t] = s;
    }
}

// ---------------------------------------------------------------- K3: hidden (+gamma fused) ; a_i ; c_j
__global__ __launch_bounds__(256) void k_hidden(const float* __restrict__ ent,
                                                const float* __restrict__ qV,
                                                const float* __restrict__ U,
                                                const float* __restrict__ bvec,
                                                const float* __restrict__ W,
                                                float* __restrict__ hidden,
                                                float* __restrict__ a_i,
                                                float* __restrict__ c_j) {
    __shared__ float e_s[D2];
    __shared__ float r_s[2][4];
    __shared__ float sig_s;
    int n = blockIdx.x, t = threadIdx.x;
    // gamma: dot(qV, ent[n]) / sqrt(D) -> sigmoid
    float part = 0.f;
    for (int k = t; k < D2; k += 256) {
        float e = ent[n * D2 + k];
        e_s[k] = e;
        part += e * qV[k];
    }
    for (int off = 32; off; off >>= 1) part += __shfl_down(part, off);
    if ((t & 63) == 0) r_s[0][t >> 6] = part;
    __syncthreads();
    if (t == 0) sig_s = sigmoidf_((r_s[0][0] + r_s[0][1] + r_s[0][2] + r_s[0][3]) / DROOT);
    __syncthreads();
    float sg = sig_s;
    float wa = 0.f, wc = 0.f;
    for (int d = t; d < DD; d += 256) {
        float s = 0.f;
        const float* Ur = U + (size_t)d * D2;
        #pragma unroll 4
        for (int k = 0; k < D2; ++k) s += e_s[k] * Ur[k];
        s = sg * s + bvec[d];
        hidden[n * DD + d] = s;
        wa += s * W[d];
        wc += s * W[DD + d];
    }
    for (int off = 32; off; off >>= 1) { wa += __shfl_down(wa, off); wc += __shfl_down(wc, off); }
    __syncthreads();
    if ((t & 63) == 0) { r_s[0][t >> 6] = wa; r_s[1][t >> 6] = wc; }
    __syncthreads();
    if (t == 0) {
        float A = 0.f, C = 0.f;
        for (int w = 0; w < 4; ++w) { A += r_s[0][w]; C += r_s[1][w]; }
        a_i[n] = A; c_j[n] = C;
    }
}

// ---------------------------------------------------------------- K4: alphas = softmax(betas, axis=1)
__global__ __launch_bounds__(256) void k_alphas(const float* __restrict__ adj,
                                                const float* __restrict__ ai,
                                                const float* __restrict__ cj,
                                                float* __restrict__ alphas) {
    __shared__ float red[4];
    __shared__ float bc[2];
    int i = blockIdx.x, j = threadIdx.x;
    float beta = 0.f;
    if (adj[i * NN + j] > 0.f) {
        float v = ai[i] + cj[j];
        beta = (v > 0.f) ? v : 0.01f * v;
    }
    float wm = beta;
    for (int off = 32; off; off >>= 1) wm = fmaxf(wm, __shfl_down(wm, off));
    if ((j & 63) == 0) red[j >> 6] = wm;
    __syncthreads();
    if (j == 0) bc[0] = fmaxf(fmaxf(red[0], red[1]), fmaxf(red[2], red[3]));
    __syncthreads();
    float e = expf(beta - bc[0]);
    float ws_ = e;
    for (int off = 32; off; off >>= 1) ws_ += __shfl_down(ws_, off);
    __syncthreads();
    if ((j & 63) == 0) red[j >> 6] = ws_;
    __syncthreads();
    if (j == 0) bc[1] = 1.f / (red[0] + red[1] + red[2] + red[3]);
    __syncthreads();
    alphas[i * NN + j] = e * bc[1];
}

// ---------------------------------------------------------------- K5: E_t (+ce fused)
__global__ __launch_bounds__(320) void k_Et(const float* __restrict__ adj,
                                            const float* __restrict__ alphas,
                                            const float* __restrict__ hidden,
                                            const float* __restrict__ w_att,
                                            const float* __restrict__ b_att,
                                            float* __restrict__ Et,
                                            float* __restrict__ ce) {
    __shared__ float w_s[NN];
    __shared__ float red5[5];
    int i = blockIdx.x, t = threadIdx.x;
    if (t < NN) w_s[t] = adj[i * NN + t] * alphas[t * NN + i];
    __syncthreads();
    float etv = 0.f;
    if (t < DD) {
        float s = 0.f;
        for (int j = 0; j < NN; ++j) s += w_s[j] * hidden[j * DD + t];
        etv = fmaxf(s, 0.f);
        Et[i * DD + t] = etv;
    }
    float pv = (t < DD) ? etv * w_att[DD + t] : 0.f;
    for (int off = 32; off; off >>= 1) pv += __shfl_down(pv, off);
    if ((t & 63) == 0) red5[t >> 6] = pv;
    __syncthreads();
    if (t == 0) ce[i] = red5[0] + red5[1] + red5[2] + red5[3] + red5[4] + b_att[1];
}

// ---------------------------------------------------------------- K6: S[l,n] (+cq fused) + rowmax
__global__ __launch_bounds__(256) void k_S(const float* __restrict__ query,
                                           const float* __restrict__ Et,
                                           const float* __restrict__ w_att,
                                           const float* __restrict__ b_att,
                                           const float* __restrict__ ce,
                                           float* __restrict__ S,
                                           float* __restrict__ rowmax) {
    __shared__ float qw[DD];
    __shared__ float red4[4];
    __shared__ float cql_s;
    int l = blockIdx.x, n = threadIdx.x;
    float part = 0.f;
    for (int d = n; d < DD; d += 256) {
        float qv = query[l * DD + d];
        qw[d] = qv * w_att[2 * DD + d];
        part += qv * w_att[d];
    }
    for (int off = 32; off; off >>= 1) part += __shfl_down(part, off);
    if ((n & 63) == 0) red4[n >> 6] = part;
    __syncthreads();
    if (n == 0) cql_s = red4[0] + red4[1] + red4[2] + red4[3] + b_att[0];
    __syncthreads();
    const float* e = Et + n * DD;
    float s = 0.f;
    for (int d = 0; d < DD; ++d) s += qw[d] * e[d];
    float val = cql_s + ce[n] + s + b_att[2];
    S[l * NN + n] = val;
    float wm = val;
    for (int off = 32; off; off >>= 1) wm = fmaxf(wm, __shfl_down(wm, off));
    __syncthreads();
    if ((n & 63) == 0) red4[n >> 6] = wm;
    __syncthreads();
    if (n == 0) rowmax[l] = fmaxf(fmaxf(red4[0], red4[1]), fmaxf(red4[2], red4[3]));
}

// ---------------------------------------------------------------- K7: q2c = softmax(rowmax) @ query  (1 block)
__global__ __launch_bounds__(320) void k_q2c(const float* __restrict__ rowmax,
                                             const float* __restrict__ query,
                                             float* __restrict__ q2c) {
    __shared__ float p[LL];
    __shared__ float red[5];
    __shared__ float bc[2];
    int t = threadIdx.x;
    float v = (t < LL) ? rowmax[t] : -1e30f;
    float wm = v;
    for (int off = 32; off; off >>= 1) wm = fmaxf(wm, __shfl_down(wm, off));
    if ((t & 63) == 0) red[t >> 6] = wm;
    __syncthreads();
    if (t == 0) {
        float m = red[0];
        for (int w = 1; w < 5; ++w) m = fmaxf(m, red[w]);
        bc[0] = m;
    }
    __syncthreads();
    float e = (t < LL) ? expf(v - bc[0]) : 0.f;
    float ws_ = e;
    for (int off = 32; off; off >>= 1) ws_ += __shfl_down(ws_, off);
    __syncthreads();
    if ((t & 63) == 0) red[t >> 6] = ws_;
    __syncthreads();
    if (t == 0) {
        float s = 0.f;
        for (int w = 0; w < 5; ++w) s += red[w];
        bc[1] = 1.f / s;
    }
    __syncthreads();
    if (t < LL) p[t] = e * bc[1];
    __syncthreads();
    if (t < DD) {
        float s = 0.f;
        for (int l = 0; l < LL; ++l) s += p[l] * query[l * DD + t];
        q2c[t] = s;
    }
}

// ---------------------------------------------------------------- K8: bidaf out = softmax(S)@Et -> concat -> @W_red.T + b
__global__ __launch_bounds__(320) void k_bidaf(const float* __restrict__ S,
                                               const float* __restrict__ rowmax,
                                               const float* __restrict__ Et,
                                               const float* __restrict__ query,
                                               const float* __restrict__ q2c,
                                               const float* __restrict__ Wred,
                                               const float* __restrict__ bred,
                                               float* __restrict__ outq) {
    __shared__ float p[NN];
    __shared__ float red5[5];
    __shared__ float xs[D4];
    __shared__ float invs;
    int l = blockIdx.x, t = threadIdx.x;
    float e = (t < NN) ? expf(S[l * NN + t] - rowmax[l]) : 0.f;
    float v = e;
    for (int off = 32; off; off >>= 1) v += __shfl_down(v, off);
    if ((t & 63) == 0) red5[t >> 6] = v;
    __syncthreads();
    if (t == 0) invs = 1.f / (red5[0] + red5[1] + red5[2] + red5[3] + red5[4]);
    __syncthreads();
    if (t < NN) p[t] = e * invs;
    __syncthreads();
    for (int d = t; d < DD; d += 320) {
        float s = 0.f;
        #pragma unroll 4
        for (int j = 0; j < NN; ++j) s += p[j] * Et[(size_t)j * DD + d];
        float qv = query[l * DD + d];
        xs[d] = qv; xs[DD + d] = s; xs[2 * DD + d] = qv * s; xs[3 * DD + d] = qv * q2c[d];
    }
    __syncthreads();
    if (t < DD) {
        float s = bred[t];
        const float* wr = Wred + (size_t)t * D4;
        #pragma unroll 4
        for (int k = 0; k < D4; ++k) s += xs[k] * wr[k];
        outq[l * DD + t] = s;
    }
}

// ---------------------------------------------------------------- K9: Xb(bf16) = [context | bin_M @ E_t | 0-pad]
__global__ __launch_bounds__(320) void k_xbuf(const float* __restrict__ ctx,
                                              const float* __restrict__ binM,
                                              const float* __restrict__ Et,
                                              ushort* __restrict__ Xb) {
    __shared__ int lst[NN];
    __shared__ int wcnt[5];
    __shared__ int total_s;
    int m = blockIdx.x, t = threadIdx.x;
    int wave = t >> 6, lane = t & 63;
    float b = (t < NN) ? binM[(size_t)m * NN + t] : 0.f;
    unsigned long long mask = __ballot(b != 0.f);
    int prefix = __popcll(mask & ((1ull << lane) - 1ull));
    if (lane == 0) wcnt[wave] = (int)__popcll(mask);
    __syncthreads();
    int wbase = 0;
    for (int w = 0; w < wave; ++w) wbase += wcnt[w];
    if (b != 0.f) lst[wbase + prefix] = t;
    if (t == 0) total_s = wcnt[0] + wcnt[1] + wcnt[2] + wcnt[3] + wcnt[4];
    __syncthreads();
    int total = total_s;
    if (t < 8) Xb[(size_t)m * KP + D2 + t] = 0;   // K padding
    if (t >= DD) return;
    Xb[(size_t)m * KP + t] = f2bf(ctx[(size_t)m * DD + t]);
    float s = 0.f;
    for (int i = 0; i < total; ++i) s += Et[(size_t)lst[i] * DD + t];
    Xb[(size_t)m * KP + DD + t] = f2bf(s);
}

// ---------------------------------------------------------------- K10: gates = Xb @ Wb^T  (bf16 MFMA, 64x64 tile)
__global__ __launch_bounds__(256) void k_gemm_gates(const ushort* __restrict__ Xb,
                                                    const ushort* __restrict__ Wb,
                                                    float* __restrict__ gates) {
    __shared__ ushort As[GM * GK];
    __shared__ ushort Bs[GN * GK];
    int m0 = blockIdx.x * GM, n0 = blockIdx.y * GN;
    int tid = threadIdx.x;
    int lane = tid & 63, w = tid >> 6;
    int wm = w >> 1, wn = w & 1;              // 2x2 waves, each 32x32 out
    int l15 = lane & 15, l4 = lane >> 4;
    f32x4 acc[2][2] = {};
    int srow = tid >> 2, kslot = tid & 3;     // staging: row, 8-ushort slot
    int sidx = srow * GK + ((kslot ^ ((srow >> 1) & 3)) << 3);   // XOR-swizzled
    for (int k0 = 0; k0 < KP; k0 += GK) {
        uint4 va = *(const uint4*)(Xb + (size_t)(m0 + srow) * KP + k0 + kslot * 8);
        uint4 vb = *(const uint4*)(Wb + (size_t)(n0 + srow) * KP + k0 + kslot * 8);
        *(uint4*)(As + sidx) = va;
        *(uint4*)(Bs + sidx) = vb;
        __syncthreads();
        bf16x8 af[2], bf[2];
        #pragma unroll
        for (int mi = 0; mi < 2; ++mi) {
            int row = wm * 32 + mi * 16 + l15;
            af[mi] = *(const bf16x8*)(As + row * GK + ((l4 ^ ((row >> 1) & 3)) << 3));
        }
        #pragma unroll
        for (int ni = 0; ni < 2; ++ni) {
            int row = wn * 32 + ni * 16 + l15;
            bf[ni] = *(const bf16x8*)(Bs + row * GK + ((l4 ^ ((row >> 1) & 3)) << 3));
        }
        #pragma unroll
        for (int mi = 0; mi < 2; ++mi)
            #pragma unroll
            for (int ni = 0; ni < 2; ++ni)
                acc[mi][ni] = __builtin_amdgcn_mfma_f32_16x16x32_bf16(af[mi], bf[ni], acc[mi][ni], 0, 0, 0);
        __syncthreads();
    }
    // C/D mapping: col = lane&15, row = (lane>>4)*4 + reg
    #pragma unroll
    for (int mi = 0; mi < 2; ++mi) {
        #pragma unroll
        for (int ni = 0; ni < 2; ++ni) {
            int gcol = n0 + wn * 32 + ni * 16 + l15;
            int grow = m0 + wm * 32 + mi * 16 + l4 * 4;
            #pragma unroll
            for (int r = 0; r < 4; ++r)
                gates[(size_t)(grow + r) * NP + gcol] = acc[mi][ni][r];
        }
    }
}

// ---------------------------------------------------------------- K11: LSTM-cell epilogue (gates layout: i|g|o, stride NP)
__global__ __launch_bounds__(320) void k_lstm(const float* __restrict__ gates,
                                              const float* __restrict__ bih,
                                              const float* __restrict__ bhh,
                                              float* __restrict__ outc) {
    int m = blockIdx.x, d = threadIdx.x;
    if (d >= DD) return;
    const float* g = gates + (size_t)m * NP;
    float gi = g[d]          + bih[d]          + bhh[d];
    float gg = g[DD + d]     + bih[2 * DD + d] + bhh[2 * DD + d];
    float go = g[2 * DD + d] + bih[3 * DD + d] + bhh[3 * DD + d];
    float c = sigmoidf_(gi) * tanhf(gg);
    outc[m * DD + d] = sigmoidf_(go) * tanhf(c);
}

// ================================================================ launch
extern "C" void kernel_launch(void* const* d_in, const int* in_sizes, int n_in,
                              void* d_out, int out_size, void* d_ws, size_t ws_size,
                              hipStream_t stream) {
    const float* context = (const float*)d_in[0];
    const float* query   = (const float*)d_in[1];
    const float* binM    = (const float*)d_in[2];
    const float* adj     = (const float*)d_in[3];
    const float* V       = (const float*)d_in[4];
    const float* U       = (const float*)d_in[5];
    const float* bvec    = (const float*)d_in[6];
    const float* W       = (const float*)d_in[7];
    const float* w_att   = (const float*)d_in[8];
    const float* b_att   = (const float*)d_in[9];
    const float* W_red   = (const float*)d_in[10];
    const float* b_red   = (const float*)d_in[11];
    const float* W_ih    = (const float*)d_in[12];
    const float* b_ih    = (const float*)d_in[13];
    const float* b_hh    = (const float*)d_in[14];

    float* ws = (float*)d_ws;
    float* ent    = ws;                 // 153600
    float* qV     = ent    + 153600;    // 608
    float* hidden = qV     + 608;       // 76800
    float* a_i    = hidden + 76800;     // 256
    float* c_j    = a_i    + 256;       // 256
    float* alphas = c_j    + 256;       // 65536
    float* Et     = alphas + 65536;     // 76800
    float* ce     = Et     + 76800;     // 256
    float* Smat   = ce     + 256;       // 32768
    float* rmax   = Smat   + 32768;     // 128
    float* q2c    = rmax   + 128;       // 304
    float* gates  = q2c    + 304;       // MM*NP = 1966080
    ushort* Xb    = (ushort*)(gates + (size_t)MM * NP);        // MM*KP ushorts
    ushort* Wb    = Xb + (size_t)MM * KP;                      // NP*KP ushorts

    float* outc = (float*)d_out;            // ctx: (M, D)
    float* outq = (float*)d_out + MM * DD;  // qry: (L, D)

    hipLaunchKernelGGL(k_convW,   dim3(NP), dim3(256), 0, stream, W_ih, Wb);
    hipLaunchKernelGGL(k_tok2ent, dim3(NN), dim3(T2E_T), 0, stream, context, binM, ent);
    hipLaunchKernelGGL(k_qprep,   dim3(1),  dim3(640), 0, stream, query, V, qV);
    hipLaunchKernelGGL(k_hidden,  dim3(NN), dim3(256), 0, stream, ent, qV, U, bvec, W, hidden, a_i, c_j);
    hipLaunchKernelGGL(k_alphas,  dim3(NN), dim3(256), 0, stream, adj, a_i, c_j, alphas);
    hipLaunchKernelGGL(k_Et,      dim3(NN), dim3(320), 0, stream, adj, alphas, hidden, w_att, b_att, Et, ce);
    hipLaunchKernelGGL(k_S,       dim3(LL), dim3(256), 0, stream, query, Et, w_att, b_att, ce, Smat, rmax);
    hipLaunchKernelGGL(k_q2c,     dim3(1),  dim3(320), 0, stream, rmax, query, q2c);
    hipLaunchKernelGGL(k_bidaf,   dim3(LL), dim3(320), 0, stream, Smat, rmax, Et, query, q2c, W_red, b_red, outq);
    hipLaunchKernelGGL(k_xbuf,    dim3(MM), dim3(320), 0, stream, context, binM, Et, Xb);
    hipLaunchKernelGGL(k_gemm_gates, dim3(MM / GM, NP / GN), dim3(256), 0, stream, Xb, Wb, gates);
    hipLaunchKernelGGL(k_lstm,    dim3(MM), dim3(320), 0, stream, gates, b_ih, b_hh, outc);
}